// Round 4
// baseline (640.631 us; speedup 1.0000x reference)
//
#include <hip/hip_runtime.h>
#include <hip/hip_cooperative_groups.h>
#include <math.h>

namespace cg = cooperative_groups;

#define BB 8192
#define DD 2048
#define BN_EPS 1e-5f

// ---------------- cooperative fused path ----------------
#define NBLK 512
#define NTHR 512
#define RPB  16   // rows per block   (NBLK * RPB == BB)
#define CPT  4    // cols per thread  (NTHR * CPT == DD)
#define NWV  (NTHR / 64)

// One cooperative kernel does all 4 layers. Each thread keeps its
// 16x4 slice of `out` in registers (all indices compile-time).
// 512 blocks x 512 thr @ <=128 VGPR -> 2 blocks/CU co-resident.
__global__ __launch_bounds__(NTHR, 4) void k_fused(
    const float* __restrict__ x, const float* __restrict__ w4,
    const float* __restrict__ b4, float* __restrict__ out,
    float* __restrict__ ws)
{
    cg::grid_group grid = cg::this_grid();
    const int t    = threadIdx.x;
    const int blk  = blockIdx.x;
    const int lane = t & 63;
    const int wv   = t >> 6;
    const int row0 = blk * RPB;
    const int c0   = t * CPT;

    float* partials = ws;                          // [NBLK][2][DD]
    float* mu_g     = ws + (size_t)NBLK * 2 * DD;  // [DD]
    float* inv_g    = mu_g + DD;                   // [DD]

    __shared__ float lds_red[NWV][RPB];
    __shared__ float lds_s[RPB];
    __shared__ float lds_st[NWV][2 * CPT];

    // v holds the (normalized) running `out`; starts as x.
    float v[RPB][CPT];
    #pragma unroll
    for (int r = 0; r < RPB; ++r)
        *(float4*)&v[r][0] = *(const float4*)(x + (size_t)(row0 + r) * DD + c0);

    for (int l = 0; l < 4; ++l) {
        // ---- row dot: s[row] = sum_d v[row,d] * w[l,d]  (block-local)
        float wr[CPT];
        *(float4*)&wr[0] = *(const float4*)(w4 + l * DD + c0);
        float p[RPB];
        #pragma unroll
        for (int r = 0; r < RPB; ++r) {
            float a = v[r][0] * wr[0];
            a = fmaf(v[r][1], wr[1], a);
            a = fmaf(v[r][2], wr[2], a);
            a = fmaf(v[r][3], wr[3], a);
            p[r] = a;
        }
        #pragma unroll
        for (int off = 32; off; off >>= 1) {
            #pragma unroll
            for (int r = 0; r < RPB; ++r)
                p[r] += __shfl_xor(p[r], off, 64);
        }
        if (lane == 0) {
            #pragma unroll
            for (int r = 0; r < RPB; ++r) lds_red[wv][r] = p[r];
        }
        __syncthreads();
        if (t < RPB) {
            float a = 0.f;
            #pragma unroll
            for (int w = 0; w < NWV; ++w) a += lds_red[w][t];
            lds_s[t] = a;
        }
        __syncthreads();

        // ---- update: v = x*s + bias + v; accumulate column partials
        float bv[CPT];
        *(float4*)&bv[0] = *(const float4*)(b4 + l * DD + c0);
        float cs[CPT], cq[CPT];
        #pragma unroll
        for (int j = 0; j < CPT; ++j) { cs[j] = 0.f; cq[j] = 0.f; }
        #pragma unroll
        for (int r = 0; r < RPB; ++r) {
            const float4 x4 = *(const float4*)(x + (size_t)(row0 + r) * DD + c0);
            const float sv = lds_s[r];
            const float xv[CPT] = { x4.x, x4.y, x4.z, x4.w };
            #pragma unroll
            for (int j = 0; j < CPT; ++j) {
                v[r][j] = fmaf(xv[j], sv, bv[j] + v[r][j]);
                cs[j] += v[r][j];
                cq[j]  = fmaf(v[r][j], v[r][j], cq[j]);
            }
        }
        {
            float* pp = partials + (size_t)blk * 2 * DD;
            *(float4*)(pp + c0)      = *(float4*)&cs[0];
            *(float4*)(pp + DD + c0) = *(float4*)&cq[0];
        }

        grid.sync();

        // ---- stats reduce: block b owns cols [4b, 4b+4); thread t reads partial t
        {
            const int cb = blk * CPT;
            const float* pb = partials + (size_t)t * 2 * DD;
            float a[CPT], q[CPT];
            *(float4*)&a[0] = *(const float4*)(pb + cb);
            *(float4*)&q[0] = *(const float4*)(pb + DD + cb);
            #pragma unroll
            for (int off = 32; off; off >>= 1) {
                #pragma unroll
                for (int j = 0; j < CPT; ++j) {
                    a[j] += __shfl_xor(a[j], off, 64);
                    q[j] += __shfl_xor(q[j], off, 64);
                }
            }
            if (lane == 0) {
                #pragma unroll
                for (int j = 0; j < CPT; ++j) {
                    lds_st[wv][j]       = a[j];
                    lds_st[wv][CPT + j] = q[j];
                }
            }
            __syncthreads();
            if (t == 0) {
                #pragma unroll
                for (int j = 0; j < CPT; ++j) {
                    float A = 0.f, Q = 0.f;
                    #pragma unroll
                    for (int w = 0; w < NWV; ++w) {
                        A += lds_st[w][j];
                        Q += lds_st[w][CPT + j];
                    }
                    const float m  = A / (float)BB;
                    const float va = fmaxf(Q / (float)BB - m * m, 0.f);
                    mu_g[cb + j]  = m;
                    inv_g[cb + j] = rsqrtf(va + BN_EPS);
                }
            }
        }

        grid.sync();

        // ---- normalize registers
        float mv[CPT], iv[CPT];
        *(float4*)&mv[0] = *(const float4*)(mu_g + c0);
        *(float4*)&iv[0] = *(const float4*)(inv_g + c0);
        #pragma unroll
        for (int r = 0; r < RPB; ++r) {
            #pragma unroll
            for (int j = 0; j < CPT; ++j)
                v[r][j] = (v[r][j] - mv[j]) * iv[j];
        }
    }

    // ---- final store
    #pragma unroll
    for (int r = 0; r < RPB; ++r)
        *(float4*)(out + (size_t)(row0 + r) * DD + c0) = *(float4*)&v[r][0];
}

// ---------------- fallback multi-kernel path (round-1, known-good) ----------------
__global__ __launch_bounds__(256) void k_dot(
    const float* __restrict__ raw, const float* __restrict__ w,
    const float* __restrict__ mu, const float* __restrict__ inv,
    float* __restrict__ s, int use_norm)
{
    const int lane = threadIdx.x & 63;
    const int wvv  = threadIdx.x >> 6;
    const int row  = blockIdx.x * 4 + wvv;
    const float* r = raw + (size_t)row * DD;
    float acc = 0.f;
    #pragma unroll
    for (int k = 0; k < DD / 256; ++k) {
        const int idx = lane * 4 + k * 256;
        const float4 rv  = *(const float4*)(r + idx);
        const float4 wv4 = *(const float4*)(w + idx);
        if (use_norm) {
            const float4 m  = *(const float4*)(mu + idx);
            const float4 iv = *(const float4*)(inv + idx);
            acc += (rv.x - m.x) * iv.x * wv4.x
                 + (rv.y - m.y) * iv.y * wv4.y
                 + (rv.z - m.z) * iv.z * wv4.z
                 + (rv.w - m.w) * iv.w * wv4.w;
        } else {
            acc += rv.x * wv4.x + rv.y * wv4.y + rv.z * wv4.z + rv.w * wv4.w;
        }
    }
    #pragma unroll
    for (int off = 32; off; off >>= 1) acc += __shfl_down(acc, off, 64);
    if (lane == 0) s[row] = acc;
}

__global__ __launch_bounds__(256) void k_upd(
    const float* __restrict__ x, const float* raw,
    const float* __restrict__ bias, const float* __restrict__ s,
    const float* __restrict__ mu, const float* __restrict__ inv,
    float* outbuf, float* __restrict__ partials,
    int rows_per_blk, int use_norm)
{
    const int t  = threadIdx.x;
    const int c0 = t * 8;
    const int row0 = blockIdx.x * rows_per_blk;
    float bv[8], mv[8], iv[8];
    *(float4*)&bv[0] = *(const float4*)(bias + c0);
    *(float4*)&bv[4] = *(const float4*)(bias + c0 + 4);
    if (use_norm) {
        *(float4*)&mv[0] = *(const float4*)(mu + c0);
        *(float4*)&mv[4] = *(const float4*)(mu + c0 + 4);
        *(float4*)&iv[0] = *(const float4*)(inv + c0);
        *(float4*)&iv[4] = *(const float4*)(inv + c0 + 4);
    } else {
        #pragma unroll
        for (int j = 0; j < 8; ++j) { mv[j] = 0.f; iv[j] = 1.f; }
    }
    float sum[8], sq[8];
    #pragma unroll
    for (int j = 0; j < 8; ++j) { sum[j] = 0.f; sq[j] = 0.f; }

    for (int r = 0; r < rows_per_blk; ++r) {
        const size_t base = (size_t)(row0 + r) * DD + c0;
        const float  sv = s[row0 + r];
        float xv[8], rv[8], vv[8];
        *(float4*)&xv[0] = *(const float4*)(x + base);
        *(float4*)&xv[4] = *(const float4*)(x + base + 4);
        *(float4*)&rv[0] = *(const float4*)(raw + base);
        *(float4*)&rv[4] = *(const float4*)(raw + base + 4);
        #pragma unroll
        for (int j = 0; j < 8; ++j) {
            vv[j] = fmaf(xv[j], sv, bv[j] + (rv[j] - mv[j]) * iv[j]);
            sum[j] += vv[j];
            sq[j]   = fmaf(vv[j], vv[j], sq[j]);
        }
        *(float4*)(outbuf + base)     = *(float4*)&vv[0];
        *(float4*)(outbuf + base + 4) = *(float4*)&vv[4];
    }
    float* p = partials + (size_t)blockIdx.x * 2 * DD;
    *(float4*)(p + c0)          = *(float4*)&sum[0];
    *(float4*)(p + c0 + 4)      = *(float4*)&sum[4];
    *(float4*)(p + DD + c0)     = *(float4*)&sq[0];
    *(float4*)(p + DD + c0 + 4) = *(float4*)&sq[4];
}

__global__ __launch_bounds__(256) void k_stats_a(
    const float* __restrict__ partials, float* __restrict__ mid, int nb_per_pg)
{
    const int pg = blockIdx.x >> 4;
    const int ec = blockIdx.x & 15;
    const int e  = ec * 256 + threadIdx.x;
    const int p0 = pg * nb_per_pg;
    float acc = 0.f;
    for (int p = 0; p < nb_per_pg; ++p)
        acc += partials[(size_t)(p0 + p) * (2 * DD) + e];
    mid[(size_t)pg * (2 * DD) + e] = acc;
}

__global__ __launch_bounds__(256) void k_stats_b(
    const float* __restrict__ mid, float* __restrict__ mu, float* __restrict__ inv)
{
    const int col = blockIdx.x * 256 + threadIdx.x;
    float sum = 0.f, sq = 0.f;
    #pragma unroll
    for (int p = 0; p < 16; ++p) {
        sum += mid[(size_t)p * 2 * DD + col];
        sq  += mid[(size_t)p * 2 * DD + DD + col];
    }
    const float m   = sum / (float)BB;
    float var = sq / (float)BB - m * m;
    var = fmaxf(var, 0.f);
    mu[col]  = m;
    inv[col] = rsqrtf(var + BN_EPS);
}

__global__ __launch_bounds__(256) void k_norm(
    float* __restrict__ out, const float* __restrict__ mu, const float* __restrict__ inv)
{
    const size_t i = ((size_t)blockIdx.x * 256 + threadIdx.x) * 4;
    const int c = (int)(i & (DD - 1));
    float4 v = *(float4*)(out + i);
    const float4 m  = *(const float4*)(mu + c);
    const float4 iv = *(const float4*)(inv + c);
    v.x = (v.x - m.x) * iv.x;
    v.y = (v.y - m.y) * iv.y;
    v.z = (v.z - m.z) * iv.z;
    v.w = (v.w - m.w) * iv.w;
    *(float4*)(out + i) = v;
}

extern "C" void kernel_launch(void* const* d_in, const int* in_sizes, int n_in,
                              void* d_out, int out_size, void* d_ws, size_t ws_size,
                              hipStream_t stream) {
    const float* x  = (const float*)d_in[0];   // [B, D]
    const float* w  = (const float*)d_in[1];   // [4, D]
    const float* bb = (const float*)d_in[2];   // [4, D]
    float* out = (float*)d_out;
    float* ws  = (float*)d_ws;

    // ---- try the cooperative fused path ----
    bool coop_ok = false;
    const size_t coop_need = ((size_t)NBLK * 2 * DD + 2 * DD) * sizeof(float);
    if (ws_size >= coop_need) {
        void* args[] = { (void*)&x, (void*)&w, (void*)&bb, (void*)&out, (void*)&ws };
        hipError_t e = hipLaunchCooperativeKernel((const void*)k_fused, dim3(NBLK),
                                                  dim3(NTHR), args, 0, stream);
        coop_ok = (e == hipSuccess);
    }
    if (coop_ok) return;

    // ---- fallback: round-1 multi-kernel path ----
    float* s_buf    = ws;
    float* mu_buf   = s_buf + BB;
    float* inv_buf  = mu_buf + DD;
    float* mid_buf  = inv_buf + DD;
    float* partials = mid_buf + 16 * 2 * DD;
    const size_t used_bytes = (size_t)(partials - ws) * sizeof(float);

    int NB = 1024;
    while (NB > 16 && used_bytes + (size_t)NB * 2 * DD * sizeof(float) > ws_size)
        NB >>= 1;
    const int rows_per_blk = BB / NB;
    const int nb_per_pg = NB / 16;

    for (int l = 0; l < 4; ++l) {
        const float* raw = (l == 0) ? x : out;
        const int use_norm = (l != 0);
        k_dot<<<BB / 4, 256, 0, stream>>>(raw, w + l * DD, mu_buf, inv_buf, s_buf, use_norm);
        k_upd<<<NB, 256, 0, stream>>>(x, raw, bb + l * DD, s_buf, mu_buf, inv_buf,
                                      out, partials, rows_per_blk, use_norm);
        k_stats_a<<<16 * 16, 256, 0, stream>>>(partials, mid_buf, nb_per_pg);
        k_stats_b<<<DD / 256, 256, 0, stream>>>(mid_buf, mu_buf, inv_buf);
    }
    k_norm<<<(BB * DD / 4) / 256, 256, 0, stream>>>(out, mu_buf, inv_buf);
}

// Round 6
// 276.111 us; speedup vs baseline: 2.3202x; 2.3202x over previous
//
#include <hip/hip_runtime.h>
#include <hip/hip_cooperative_groups.h>
#include <math.h>

namespace cg = cooperative_groups;

#define BB 8192
#define DD 2048
#define BN_EPS 1e-5f

// ---------------- cooperative fused path ----------------
#define NBLK 512
#define NTHR 512
#define RPB  16   // rows per block   (NBLK * RPB == BB)
#define CPT  4    // cols per thread  (NTHR * CPT == DD)
#define NWV  (NTHR / 64)

// One cooperative kernel does all 4 layers; each thread keeps its 16x4
// slice of `out` in registers (64 VGPRs of state).
// History: (512,4) -> 64-VGPR cap, v spilled, 640us. No bound -> >128 VGPR,
// 1 blk/CU, 512-block grid NOT co-resident, grid.sync deadlock (ROCm coop
// launch does NOT validate co-residency). So: no occupancy arg, pressure
// trimmed below, and kernel_launch verifies 2 blocks/CU via occupancy query
// before taking this path.
__global__ __launch_bounds__(NTHR) void k_fused(
    const float* __restrict__ x, const float* __restrict__ w4,
    const float* __restrict__ b4, float* __restrict__ out,
    float* __restrict__ ws)
{
    cg::grid_group grid = cg::this_grid();
    const int t    = threadIdx.x;
    const int blk  = blockIdx.x;
    const int lane = t & 63;
    const int wv   = t >> 6;
    const int row0 = blk * RPB;
    const int c0   = t * CPT;

    float* partials = ws;                          // [NBLK][2][DD]
    float* mu_g     = ws + (size_t)NBLK * 2 * DD;  // [DD]
    float* inv_g    = mu_g + DD;                   // [DD]

    __shared__ float lds_red[NWV][RPB];
    __shared__ float lds_s[RPB];
    __shared__ float lds_st[NWV][2 * CPT];

    // v holds the (normalized) running `out`; starts as x.
    float v[RPB][CPT];
    {
        const float* xp = x + (size_t)row0 * DD + c0;
        #pragma unroll
        for (int r = 0; r < RPB; ++r) {
            *(float4*)&v[r][0] = *(const float4*)xp;
            xp += DD;
        }
    }

    for (int l = 0; l < 4; ++l) {
        // ---- row dot: s[row] = sum_d v[row,d] * w[l,d]  (block-local)
        // chunked 8 rows at a time to keep peak register pressure down
        float wr[CPT];
        *(float4*)&wr[0] = *(const float4*)(w4 + l * DD + c0);
        #pragma unroll
        for (int half = 0; half < 2; ++half) {
            float p[8];
            #pragma unroll
            for (int i = 0; i < 8; ++i) {
                const int r = half * 8 + i;
                float a = v[r][0] * wr[0];
                a = fmaf(v[r][1], wr[1], a);
                a = fmaf(v[r][2], wr[2], a);
                a = fmaf(v[r][3], wr[3], a);
                p[i] = a;
            }
            #pragma unroll
            for (int off = 32; off; off >>= 1) {
                #pragma unroll
                for (int i = 0; i < 8; ++i)
                    p[i] += __shfl_xor(p[i], off, 64);
            }
            if (lane == 0) {
                #pragma unroll
                for (int i = 0; i < 8; ++i) lds_red[wv][half * 8 + i] = p[i];
            }
        }
        __syncthreads();
        if (t < RPB) {
            float a = 0.f;
            #pragma unroll
            for (int w = 0; w < NWV; ++w) a += lds_red[w][t];
            lds_s[t] = a;
        }
        __syncthreads();

        // ---- update: v = x*s + bias + v  (running pointer, short live ranges)
        float bv[CPT];
        *(float4*)&bv[0] = *(const float4*)(b4 + l * DD + c0);
        {
            const float* xp = x + (size_t)row0 * DD + c0;
            #pragma unroll
            for (int r = 0; r < RPB; ++r) {
                const float4 x4 = *(const float4*)xp;
                xp += DD;
                const float sv = lds_s[r];
                v[r][0] = fmaf(x4.x, sv, bv[0] + v[r][0]);
                v[r][1] = fmaf(x4.y, sv, bv[1] + v[r][1]);
                v[r][2] = fmaf(x4.z, sv, bv[2] + v[r][2]);
                v[r][3] = fmaf(x4.w, sv, bv[3] + v[r][3]);
            }
        }

        // ---- column partials (register-only post-pass over v)
        {
            float cs[CPT], cq[CPT];
            #pragma unroll
            for (int j = 0; j < CPT; ++j) { cs[j] = 0.f; cq[j] = 0.f; }
            #pragma unroll
            for (int r = 0; r < RPB; ++r) {
                #pragma unroll
                for (int j = 0; j < CPT; ++j) {
                    cs[j] += v[r][j];
                    cq[j]  = fmaf(v[r][j], v[r][j], cq[j]);
                }
            }
            float* pp = partials + (size_t)blk * 2 * DD;
            *(float4*)(pp + c0)      = *(float4*)&cs[0];
            *(float4*)(pp + DD + c0) = *(float4*)&cq[0];
        }

        grid.sync();

        // ---- stats reduce: block b owns cols [4b,4b+4); thread t reads partial t
        {
            const int cb = blk * CPT;
            const float* pb = partials + (size_t)t * 2 * DD;
            float a[CPT], q[CPT];
            *(float4*)&a[0] = *(const float4*)(pb + cb);
            *(float4*)&q[0] = *(const float4*)(pb + DD + cb);
            #pragma unroll
            for (int off = 32; off; off >>= 1) {
                #pragma unroll
                for (int j = 0; j < CPT; ++j) {
                    a[j] += __shfl_xor(a[j], off, 64);
                    q[j] += __shfl_xor(q[j], off, 64);
                }
            }
            if (lane == 0) {
                #pragma unroll
                for (int j = 0; j < CPT; ++j) {
                    lds_st[wv][j]       = a[j];
                    lds_st[wv][CPT + j] = q[j];
                }
            }
            __syncthreads();
            if (t == 0) {
                #pragma unroll
                for (int j = 0; j < CPT; ++j) {
                    float A = 0.f, Q = 0.f;
                    #pragma unroll
                    for (int w = 0; w < NWV; ++w) {
                        A += lds_st[w][j];
                        Q += lds_st[w][CPT + j];
                    }
                    const float m  = A / (float)BB;
                    const float va = fmaxf(Q / (float)BB - m * m, 0.f);
                    mu_g[cb + j]  = m;
                    inv_g[cb + j] = rsqrtf(va + BN_EPS);
                }
            }
        }

        grid.sync();

        // ---- normalize registers
        {
            float mv[CPT], iv[CPT];
            *(float4*)&mv[0] = *(const float4*)(mu_g + c0);
            *(float4*)&iv[0] = *(const float4*)(inv_g + c0);
            #pragma unroll
            for (int r = 0; r < RPB; ++r) {
                #pragma unroll
                for (int j = 0; j < CPT; ++j)
                    v[r][j] = (v[r][j] - mv[j]) * iv[j];
            }
        }
    }

    // ---- final store
    {
        float* op = out + (size_t)row0 * DD + c0;
        #pragma unroll
        for (int r = 0; r < RPB; ++r) {
            *(float4*)op = *(float4*)&v[r][0];
            op += DD;
        }
    }
}

// ---------------- fallback multi-kernel path (round-1, known-good) ----------------
__global__ __launch_bounds__(256) void k_dot(
    const float* __restrict__ raw, const float* __restrict__ w,
    const float* __restrict__ mu, const float* __restrict__ inv,
    float* __restrict__ s, int use_norm)
{
    const int lane = threadIdx.x & 63;
    const int wvv  = threadIdx.x >> 6;
    const int row  = blockIdx.x * 4 + wvv;
    const float* r = raw + (size_t)row * DD;
    float acc = 0.f;
    #pragma unroll
    for (int k = 0; k < DD / 256; ++k) {
        const int idx = lane * 4 + k * 256;
        const float4 rv  = *(const float4*)(r + idx);
        const float4 wv4 = *(const float4*)(w + idx);
        if (use_norm) {
            const float4 m  = *(const float4*)(mu + idx);
            const float4 iv = *(const float4*)(inv + idx);
            acc += (rv.x - m.x) * iv.x * wv4.x
                 + (rv.y - m.y) * iv.y * wv4.y
                 + (rv.z - m.z) * iv.z * wv4.z
                 + (rv.w - m.w) * iv.w * wv4.w;
        } else {
            acc += rv.x * wv4.x + rv.y * wv4.y + rv.z * wv4.z + rv.w * wv4.w;
        }
    }
    #pragma unroll
    for (int off = 32; off; off >>= 1) acc += __shfl_down(acc, off, 64);
    if (lane == 0) s[row] = acc;
}

__global__ __launch_bounds__(256) void k_upd(
    const float* __restrict__ x, const float* raw,
    const float* __restrict__ bias, const float* __restrict__ s,
    const float* __restrict__ mu, const float* __restrict__ inv,
    float* outbuf, float* __restrict__ partials,
    int rows_per_blk, int use_norm)
{
    const int t  = threadIdx.x;
    const int c0 = t * 8;
    const int row0 = blockIdx.x * rows_per_blk;
    float bv[8], mv[8], iv[8];
    *(float4*)&bv[0] = *(const float4*)(bias + c0);
    *(float4*)&bv[4] = *(const float4*)(bias + c0 + 4);
    if (use_norm) {
        *(float4*)&mv[0] = *(const float4*)(mu + c0);
        *(float4*)&mv[4] = *(const float4*)(mu + c0 + 4);
        *(float4*)&iv[0] = *(const float4*)(inv + c0);
        *(float4*)&iv[4] = *(const float4*)(inv + c0 + 4);
    } else {
        #pragma unroll
        for (int j = 0; j < 8; ++j) { mv[j] = 0.f; iv[j] = 1.f; }
    }
    float sum[8], sq[8];
    #pragma unroll
    for (int j = 0; j < 8; ++j) { sum[j] = 0.f; sq[j] = 0.f; }

    for (int r = 0; r < rows_per_blk; ++r) {
        const size_t base = (size_t)(row0 + r) * DD + c0;
        const float  sv = s[row0 + r];
        float xv[8], rv[8], vv[8];
        *(float4*)&xv[0] = *(const float4*)(x + base);
        *(float4*)&xv[4] = *(const float4*)(x + base + 4);
        *(float4*)&rv[0] = *(const float4*)(raw + base);
        *(float4*)&rv[4] = *(const float4*)(raw + base + 4);
        #pragma unroll
        for (int j = 0; j < 8; ++j) {
            vv[j] = fmaf(xv[j], sv, bv[j] + (rv[j] - mv[j]) * iv[j]);
            sum[j] += vv[j];
            sq[j]   = fmaf(vv[j], vv[j], sq[j]);
        }
        *(float4*)(outbuf + base)     = *(float4*)&vv[0];
        *(float4*)(outbuf + base + 4) = *(float4*)&vv[4];
    }
    float* p = partials + (size_t)blockIdx.x * 2 * DD;
    *(float4*)(p + c0)          = *(float4*)&sum[0];
    *(float4*)(p + c0 + 4)      = *(float4*)&sum[4];
    *(float4*)(p + DD + c0)     = *(float4*)&sq[0];
    *(float4*)(p + DD + c0 + 4) = *(float4*)&sq[4];
}

__global__ __launch_bounds__(256) void k_stats_a(
    const float* __restrict__ partials, float* __restrict__ mid, int nb_per_pg)
{
    const int pg = blockIdx.x >> 4;
    const int ec = blockIdx.x & 15;
    const int e  = ec * 256 + threadIdx.x;
    const int p0 = pg * nb_per_pg;
    float acc = 0.f;
    for (int p = 0; p < nb_per_pg; ++p)
        acc += partials[(size_t)(p0 + p) * (2 * DD) + e];
    mid[(size_t)pg * (2 * DD) + e] = acc;
}

__global__ __launch_bounds__(256) void k_stats_b(
    const float* __restrict__ mid, float* __restrict__ mu, float* __restrict__ inv)
{
    const int col = blockIdx.x * 256 + threadIdx.x;
    float sum = 0.f, sq = 0.f;
    #pragma unroll
    for (int p = 0; p < 16; ++p) {
        sum += mid[(size_t)p * 2 * DD + col];
        sq  += mid[(size_t)p * 2 * DD + DD + col];
    }
    const float m   = sum / (float)BB;
    float var = sq / (float)BB - m * m;
    var = fmaxf(var, 0.f);
    mu[col]  = m;
    inv[col] = rsqrtf(var + BN_EPS);
}

__global__ __launch_bounds__(256) void k_norm(
    float* __restrict__ out, const float* __restrict__ mu, const float* __restrict__ inv)
{
    const size_t i = ((size_t)blockIdx.x * 256 + threadIdx.x) * 4;
    const int c = (int)(i & (DD - 1));
    float4 v = *(float4*)(out + i);
    const float4 m  = *(const float4*)(mu + c);
    const float4 iv = *(const float4*)(inv + c);
    v.x = (v.x - m.x) * iv.x;
    v.y = (v.y - m.y) * iv.y;
    v.z = (v.z - m.z) * iv.z;
    v.w = (v.w - m.w) * iv.w;
    *(float4*)(out + i) = v;
}

extern "C" void kernel_launch(void* const* d_in, const int* in_sizes, int n_in,
                              void* d_out, int out_size, void* d_ws, size_t ws_size,
                              hipStream_t stream) {
    const float* x  = (const float*)d_in[0];   // [B, D]
    const float* w  = (const float*)d_in[1];   // [4, D]
    const float* bb = (const float*)d_in[2];   // [4, D]
    float* out = (float*)d_out;
    float* ws  = (float*)d_ws;

    // ---- coop path, only if provably co-resident (round-5 hang: ROCm does
    // NOT validate co-residency; an oversubscribed grid deadlocks grid.sync)
    bool coop_ok = false;
    const size_t coop_need = ((size_t)NBLK * 2 * DD + 2 * DD) * sizeof(float);
    if (ws_size >= coop_need) {
        int blocks_per_cu = 0;
        hipError_t qe = hipOccupancyMaxActiveBlocksPerMultiprocessor(
            &blocks_per_cu, (const void*)k_fused, NTHR, 0);
        if (qe == hipSuccess && blocks_per_cu >= (NBLK + 255) / 256) {
            void* args[] = { (void*)&x, (void*)&w, (void*)&bb, (void*)&out, (void*)&ws };
            hipError_t e = hipLaunchCooperativeKernel((const void*)k_fused, dim3(NBLK),
                                                      dim3(NTHR), args, 0, stream);
            coop_ok = (e == hipSuccess);
        }
    }
    if (coop_ok) return;

    // ---- fallback: round-1 multi-kernel path (known-good, 274us)
    float* s_buf    = ws;
    float* mu_buf   = s_buf + BB;
    float* inv_buf  = mu_buf + DD;
    float* mid_buf  = inv_buf + DD;
    float* partials = mid_buf + 16 * 2 * DD;
    const size_t used_bytes = (size_t)(partials - ws) * sizeof(float);

    int NB = 1024;
    while (NB > 16 && used_bytes + (size_t)NB * 2 * DD * sizeof(float) > ws_size)
        NB >>= 1;
    const int rows_per_blk = BB / NB;
    const int nb_per_pg = NB / 16;

    for (int l = 0; l < 4; ++l) {
        const float* raw = (l == 0) ? x : out;
        const int use_norm = (l != 0);
        k_dot<<<BB / 4, 256, 0, stream>>>(raw, w + l * DD, mu_buf, inv_buf, s_buf, use_norm);
        k_upd<<<NB, 256, 0, stream>>>(x, raw, bb + l * DD, s_buf, mu_buf, inv_buf,
                                      out, partials, rows_per_blk, use_norm);
        k_stats_a<<<16 * 16, 256, 0, stream>>>(partials, mid_buf, nb_per_pg);
        k_stats_b<<<DD / 256, 256, 0, stream>>>(mid_buf, mu_buf, inv_buf);
    }
    k_norm<<<(BB * DD / 4) / 256, 256, 0, stream>>>(out, mu_buf, inv_buf);
}

// Round 7
// 275.017 us; speedup vs baseline: 2.3294x; 1.0040x over previous
//
#include <hip/hip_runtime.h>
#include <hip/hip_cooperative_groups.h>
#include <math.h>

namespace cg = cooperative_groups;

#define BB 8192
#define DD 2048
#define BN_EPS 1e-5f

// ---------------- cooperative fused path ----------------
#define NBLK 256
#define NTHR 512
#define RPB  32   // rows per block   (NBLK * RPB == BB)
#define CPT  4    // cols per thread  (NTHR * CPT == DD)
#define NWV  (NTHR / 64)

// One cooperative kernel does all 4 layers; each thread keeps its 32x4
// slice of `out` in registers (128 VGPRs of state, ~200 total).
// Geometry: 256 blocks x 512 thr, 1 block/CU at <=256 VGPR (2 waves/SIMD).
// Ledger: (512,4)->64-reg cap,spill,640us; unbounded 512blk ->>128 reg,
// 1 blk/CU of a 512-block grid, grid.sync deadlock; 512blk@128-target ->
// occupancy query rejected, clean 276us fallback. (512,1) caps at 256
// under BOTH observed interpretations of the 2nd arg.
__global__ __launch_bounds__(NTHR, 1) void k_fused(
    const float* __restrict__ x, const float* __restrict__ w4,
    const float* __restrict__ b4, float* __restrict__ out,
    float* __restrict__ ws)
{
    cg::grid_group grid = cg::this_grid();
    const int t    = threadIdx.x;
    const int blk  = blockIdx.x;
    const int lane = t & 63;
    const int wv   = t >> 6;
    const int row0 = blk * RPB;
    const int c0   = t * CPT;

    float* partials = ws;                          // [NBLK][2][DD]
    float* mu_g     = ws + (size_t)NBLK * 2 * DD;  // [DD]
    float* inv_g    = mu_g + DD;                   // [DD]

    __shared__ float lds_red[NWV][RPB];   // 8 x 32
    __shared__ float lds_s[RPB];          // 32
    __shared__ float lds_st[4][16];       // stats cross-wave (4 active waves)

    // v holds the (normalized) running `out`; starts as x.
    float v[RPB][CPT];
    {
        const float* xp = x + (size_t)row0 * DD + c0;
        #pragma unroll
        for (int r = 0; r < RPB; ++r) {
            *(float4*)&v[r][0] = *(const float4*)xp;
            xp += DD;
        }
    }

    for (int l = 0; l < 4; ++l) {
        // ---- row dot: s[row] = sum_d v[row,d] * w[l,d]  (block-local)
        // chunked 8 rows at a time to bound peak register pressure
        {
            float wr[CPT];
            *(float4*)&wr[0] = *(const float4*)(w4 + l * DD + c0);
            #pragma unroll
            for (int ch = 0; ch < RPB / 8; ++ch) {
                float p[8];
                #pragma unroll
                for (int i = 0; i < 8; ++i) {
                    const int r = ch * 8 + i;
                    float a = v[r][0] * wr[0];
                    a = fmaf(v[r][1], wr[1], a);
                    a = fmaf(v[r][2], wr[2], a);
                    a = fmaf(v[r][3], wr[3], a);
                    p[i] = a;
                }
                #pragma unroll
                for (int off = 32; off; off >>= 1) {
                    #pragma unroll
                    for (int i = 0; i < 8; ++i)
                        p[i] += __shfl_xor(p[i], off, 64);
                }
                if (lane == 0) {
                    #pragma unroll
                    for (int i = 0; i < 8; ++i) lds_red[wv][ch * 8 + i] = p[i];
                }
            }
        }
        __syncthreads();
        if (t < RPB) {
            float a = 0.f;
            #pragma unroll
            for (int w = 0; w < NWV; ++w) a += lds_red[w][t];
            lds_s[t] = a;
        }
        __syncthreads();

        // ---- update: v = x*s + bias + v  (running pointer, short live ranges)
        {
            float bv[CPT];
            *(float4*)&bv[0] = *(const float4*)(b4 + l * DD + c0);
            const float* xp = x + (size_t)row0 * DD + c0;
            #pragma unroll
            for (int r = 0; r < RPB; ++r) {
                const float4 x4 = *(const float4*)xp;
                xp += DD;
                const float sv = lds_s[r];
                v[r][0] = fmaf(x4.x, sv, bv[0] + v[r][0]);
                v[r][1] = fmaf(x4.y, sv, bv[1] + v[r][1]);
                v[r][2] = fmaf(x4.z, sv, bv[2] + v[r][2]);
                v[r][3] = fmaf(x4.w, sv, bv[3] + v[r][3]);
            }
        }

        // ---- column partials (register-only post-pass over v)
        {
            float cs[CPT], cq[CPT];
            #pragma unroll
            for (int j = 0; j < CPT; ++j) { cs[j] = 0.f; cq[j] = 0.f; }
            #pragma unroll
            for (int r = 0; r < RPB; ++r) {
                #pragma unroll
                for (int j = 0; j < CPT; ++j) {
                    cs[j] += v[r][j];
                    cq[j]  = fmaf(v[r][j], v[r][j], cq[j]);
                }
            }
            float* pp = partials + (size_t)blk * 2 * DD;
            *(float4*)(pp + c0)      = *(float4*)&cs[0];
            *(float4*)(pp + DD + c0) = *(float4*)&cq[0];
        }

        grid.sync();

        // ---- stats reduce: block b owns cols [8b, 8b+8)
        // threads 0..255 read partial-set t; butterfly within 4 waves; combine.
        {
            const int cb = blk * 8;
            if (t < NBLK) {
                const float* pb = partials + (size_t)t * 2 * DD;
                float a[8], q[8];
                *(float4*)&a[0] = *(const float4*)(pb + cb);
                *(float4*)&a[4] = *(const float4*)(pb + cb + 4);
                *(float4*)&q[0] = *(const float4*)(pb + DD + cb);
                *(float4*)&q[4] = *(const float4*)(pb + DD + cb + 4);
                #pragma unroll
                for (int off = 32; off; off >>= 1) {
                    #pragma unroll
                    for (int j = 0; j < 8; ++j) {
                        a[j] += __shfl_xor(a[j], off, 64);
                        q[j] += __shfl_xor(q[j], off, 64);
                    }
                }
                if (lane == 0) {
                    #pragma unroll
                    for (int j = 0; j < 8; ++j) {
                        lds_st[wv][j]     = a[j];
                        lds_st[wv][8 + j] = q[j];
                    }
                }
            }
            __syncthreads();
            if (t == 0) {
                #pragma unroll
                for (int j = 0; j < 8; ++j) {
                    float A = lds_st[0][j] + lds_st[1][j] + lds_st[2][j] + lds_st[3][j];
                    float Q = lds_st[0][8 + j] + lds_st[1][8 + j] + lds_st[2][8 + j] + lds_st[3][8 + j];
                    const float m  = A / (float)BB;
                    const float va = fmaxf(Q / (float)BB - m * m, 0.f);
                    mu_g[cb + j]  = m;
                    inv_g[cb + j] = rsqrtf(va + BN_EPS);
                }
            }
        }

        grid.sync();

        // ---- normalize registers
        {
            float mv[CPT], iv[CPT];
            *(float4*)&mv[0] = *(const float4*)(mu_g + c0);
            *(float4*)&iv[0] = *(const float4*)(inv_g + c0);
            #pragma unroll
            for (int r = 0; r < RPB; ++r) {
                #pragma unroll
                for (int j = 0; j < CPT; ++j)
                    v[r][j] = (v[r][j] - mv[j]) * iv[j];
            }
        }
    }

    // ---- final store
    {
        float* op = out + (size_t)row0 * DD + c0;
        #pragma unroll
        for (int r = 0; r < RPB; ++r) {
            *(float4*)op = *(float4*)&v[r][0];
            op += DD;
        }
    }
}

// ---------------- fallback multi-kernel path (round-1, known-good) ----------------
__global__ __launch_bounds__(256) void k_dot(
    const float* __restrict__ raw, const float* __restrict__ w,
    const float* __restrict__ mu, const float* __restrict__ inv,
    float* __restrict__ s, int use_norm)
{
    const int lane = threadIdx.x & 63;
    const int wvv  = threadIdx.x >> 6;
    const int row  = blockIdx.x * 4 + wvv;
    const float* r = raw + (size_t)row * DD;
    float acc = 0.f;
    #pragma unroll
    for (int k = 0; k < DD / 256; ++k) {
        const int idx = lane * 4 + k * 256;
        const float4 rv  = *(const float4*)(r + idx);
        const float4 wv4 = *(const float4*)(w + idx);
        if (use_norm) {
            const float4 m  = *(const float4*)(mu + idx);
            const float4 iv = *(const float4*)(inv + idx);
            acc += (rv.x - m.x) * iv.x * wv4.x
                 + (rv.y - m.y) * iv.y * wv4.y
                 + (rv.z - m.z) * iv.z * wv4.z
                 + (rv.w - m.w) * iv.w * wv4.w;
        } else {
            acc += rv.x * wv4.x + rv.y * wv4.y + rv.z * wv4.z + rv.w * wv4.w;
        }
    }
    #pragma unroll
    for (int off = 32; off; off >>= 1) acc += __shfl_down(acc, off, 64);
    if (lane == 0) s[row] = acc;
}

__global__ __launch_bounds__(256) void k_upd(
    const float* __restrict__ x, const float* raw,
    const float* __restrict__ bias, const float* __restrict__ s,
    const float* __restrict__ mu, const float* __restrict__ inv,
    float* outbuf, float* __restrict__ partials,
    int rows_per_blk, int use_norm)
{
    const int t  = threadIdx.x;
    const int c0 = t * 8;
    const int row0 = blockIdx.x * rows_per_blk;
    float bv[8], mv[8], iv[8];
    *(float4*)&bv[0] = *(const float4*)(bias + c0);
    *(float4*)&bv[4] = *(const float4*)(bias + c0 + 4);
    if (use_norm) {
        *(float4*)&mv[0] = *(const float4*)(mu + c0);
        *(float4*)&mv[4] = *(const float4*)(mu + c0 + 4);
        *(float4*)&iv[0] = *(const float4*)(inv + c0);
        *(float4*)&iv[4] = *(const float4*)(inv + c0 + 4);
    } else {
        #pragma unroll
        for (int j = 0; j < 8; ++j) { mv[j] = 0.f; iv[j] = 1.f; }
    }
    float sum[8], sq[8];
    #pragma unroll
    for (int j = 0; j < 8; ++j) { sum[j] = 0.f; sq[j] = 0.f; }

    for (int r = 0; r < rows_per_blk; ++r) {
        const size_t base = (size_t)(row0 + r) * DD + c0;
        const float  sv = s[row0 + r];
        float xv[8], rv[8], vv[8];
        *(float4*)&xv[0] = *(const float4*)(x + base);
        *(float4*)&xv[4] = *(const float4*)(x + base + 4);
        *(float4*)&rv[0] = *(const float4*)(raw + base);
        *(float4*)&rv[4] = *(const float4*)(raw + base + 4);
        #pragma unroll
        for (int j = 0; j < 8; ++j) {
            vv[j] = fmaf(xv[j], sv, bv[j] + (rv[j] - mv[j]) * iv[j]);
            sum[j] += vv[j];
            sq[j]   = fmaf(vv[j], vv[j], sq[j]);
        }
        *(float4*)(outbuf + base)     = *(float4*)&vv[0];
        *(float4*)(outbuf + base + 4) = *(float4*)&vv[4];
    }
    float* p = partials + (size_t)blockIdx.x * 2 * DD;
    *(float4*)(p + c0)          = *(float4*)&sum[0];
    *(float4*)(p + c0 + 4)      = *(float4*)&sum[4];
    *(float4*)(p + DD + c0)     = *(float4*)&sq[0];
    *(float4*)(p + DD + c0 + 4) = *(float4*)&sq[4];
}

__global__ __launch_bounds__(256) void k_stats_a(
    const float* __restrict__ partials, float* __restrict__ mid, int nb_per_pg)
{
    const int pg = blockIdx.x >> 4;
    const int ec = blockIdx.x & 15;
    const int e  = ec * 256 + threadIdx.x;
    const int p0 = pg * nb_per_pg;
    float acc = 0.f;
    for (int p = 0; p < nb_per_pg; ++p)
        acc += partials[(size_t)(p0 + p) * (2 * DD) + e];
    mid[(size_t)pg * (2 * DD) + e] = acc;
}

__global__ __launch_bounds__(256) void k_stats_b(
    const float* __restrict__ mid, float* __restrict__ mu, float* __restrict__ inv)
{
    const int col = blockIdx.x * 256 + threadIdx.x;
    float sum = 0.f, sq = 0.f;
    #pragma unroll
    for (int p = 0; p < 16; ++p) {
        sum += mid[(size_t)p * 2 * DD + col];
        sq  += mid[(size_t)p * 2 * DD + DD + col];
    }
    const float m   = sum / (float)BB;
    float var = sq / (float)BB - m * m;
    var = fmaxf(var, 0.f);
    mu[col]  = m;
    inv[col] = rsqrtf(var + BN_EPS);
}

__global__ __launch_bounds__(256) void k_norm(
    float* __restrict__ out, const float* __restrict__ mu, const float* __restrict__ inv)
{
    const size_t i = ((size_t)blockIdx.x * 256 + threadIdx.x) * 4;
    const int c = (int)(i & (DD - 1));
    float4 v = *(float4*)(out + i);
    const float4 m  = *(const float4*)(mu + c);
    const float4 iv = *(const float4*)(inv + c);
    v.x = (v.x - m.x) * iv.x;
    v.y = (v.y - m.y) * iv.y;
    v.z = (v.z - m.z) * iv.z;
    v.w = (v.w - m.w) * iv.w;
    *(float4*)(out + i) = v;
}

extern "C" void kernel_launch(void* const* d_in, const int* in_sizes, int n_in,
                              void* d_out, int out_size, void* d_ws, size_t ws_size,
                              hipStream_t stream) {
    const float* x  = (const float*)d_in[0];   // [B, D]
    const float* w  = (const float*)d_in[1];   // [4, D]
    const float* bb = (const float*)d_in[2];   // [4, D]
    float* out = (float*)d_out;
    float* ws  = (float*)d_ws;

    // ---- coop path, only if provably co-resident (ROCm coop launch does NOT
    // validate co-residency; an oversubscribed grid deadlocks grid.sync)
    bool coop_ok = false;
    const size_t coop_need = ((size_t)NBLK * 2 * DD + 2 * DD) * sizeof(float);
    if (ws_size >= coop_need) {
        int blocks_per_cu = 0;
        hipError_t qe = hipOccupancyMaxActiveBlocksPerMultiprocessor(
            &blocks_per_cu, (const void*)k_fused, NTHR, 0);
        if (qe == hipSuccess && blocks_per_cu >= 1) {   // 256 blocks / 256 CUs
            void* args[] = { (void*)&x, (void*)&w, (void*)&bb, (void*)&out, (void*)&ws };
            hipError_t e = hipLaunchCooperativeKernel((const void*)k_fused, dim3(NBLK),
                                                      dim3(NTHR), args, 0, stream);
            coop_ok = (e == hipSuccess);
        }
    }
    if (coop_ok) return;

    // ---- fallback: round-1 multi-kernel path (known-good, ~276us)
    float* s_buf    = ws;
    float* mu_buf   = s_buf + BB;
    float* inv_buf  = mu_buf + DD;
    float* mid_buf  = inv_buf + DD;
    float* partials = mid_buf + 16 * 2 * DD;
    const size_t used_bytes = (size_t)(partials - ws) * sizeof(float);

    int NB = 1024;
    while (NB > 16 && used_bytes + (size_t)NB * 2 * DD * sizeof(float) > ws_size)
        NB >>= 1;
    const int rows_per_blk = BB / NB;
    const int nb_per_pg = NB / 16;

    for (int l = 0; l < 4; ++l) {
        const float* raw = (l == 0) ? x : out;
        const int use_norm = (l != 0);
        k_dot<<<BB / 4, 256, 0, stream>>>(raw, w + l * DD, mu_buf, inv_buf, s_buf, use_norm);
        k_upd<<<NB, 256, 0, stream>>>(x, raw, bb + l * DD, s_buf, mu_buf, inv_buf,
                                      out, partials, rows_per_blk, use_norm);
        k_stats_a<<<16 * 16, 256, 0, stream>>>(partials, mid_buf, nb_per_pg);
        k_stats_b<<<DD / 256, 256, 0, stream>>>(mid_buf, mu_buf, inv_buf);
    }
    k_norm<<<(BB * DD / 4) / 256, 256, 0, stream>>>(out, mu_buf, inv_buf);
}